// Round 2
// baseline (802.922 us; speedup 1.0000x reference)
//
#include <hip/hip_runtime.h>
#include <stdint.h>

#define NN 50000   // nodes
#define NE 100000  // edges
#define DD 768     // feature dim
#define KC 1536    // concatenated K = 2*DD
#define SCAN_B 196 // ceil(NN/256)
#define NTM 391    // ceil(NN/128)
#define NTN 6      // DD/128

typedef __attribute__((ext_vector_type(8))) __bf16 bf16x8;
typedef __attribute__((ext_vector_type(4))) float floatx4;

static __device__ __forceinline__ float bf2f(unsigned short u) {
    union { unsigned int u; float f; } c; c.u = ((unsigned int)u) << 16; return c.f;
}
static __device__ __forceinline__ unsigned short f2bf(float f) {
    union { float f; unsigned int u; } c; c.f = f;
    return (unsigned short)((c.u + 0x7FFFu + ((c.u >> 16) & 1u)) >> 16);
}

// async global->LDS, 16B per lane; LDS dst = wave-uniform base + lane*16
static __device__ __forceinline__ void gld16(const void* g, void* l) {
    __builtin_amdgcn_global_load_lds(
        (const __attribute__((address_space(1))) unsigned int*)g,
        (__attribute__((address_space(3))) unsigned int*)l, 16, 0, 0);
}

// ---------------- prep kernels ----------------

// x (f32) -> bf16 into right half of Acat1 ([n][768..1535])
__global__ __launch_bounds__(192) void k_convert_x(const float* __restrict__ x,
                                                   unsigned short* __restrict__ acat) {
    const int n = blockIdx.x;
    const int c = threadIdx.x * 4;
    const float4 v = *(const float4*)(x + (size_t)n * DD + c);
    ushort4 o;
    o.x = f2bf(v.x); o.y = f2bf(v.y); o.z = f2bf(v.z); o.w = f2bf(v.w);
    *(ushort4*)(acat + (size_t)n * KC + DD + c) = o;
}

// Bcat[layer][j][k] = k<768 ? Wl[j][k] : Wr[j][k-768]   (bf16)
__global__ __launch_bounds__(384) void k_convert_w(const float* __restrict__ W1l,
                                                   const float* __restrict__ W1r,
                                                   const float* __restrict__ W2l,
                                                   const float* __restrict__ W2r,
                                                   unsigned short* __restrict__ B1,
                                                   unsigned short* __restrict__ B2) {
    const int j = blockIdx.x;
    const int layer = blockIdx.y;
    const int k = threadIdx.x * 4;
    const float* Wl = layer ? W2l : W1l;
    const float* Wr = layer ? W2r : W1r;
    unsigned short* B = layer ? B2 : B1;
    const float4 v = (k < DD) ? *(const float4*)(Wl + (size_t)j * DD + k)
                              : *(const float4*)(Wr + (size_t)j * DD + (k - DD));
    ushort4 o; o.x = f2bf(v.x); o.y = f2bf(v.y); o.z = f2bf(v.z); o.w = f2bf(v.w);
    *(ushort4*)(B + (size_t)j * KC + k) = o;
}

// ---------------- CSR build (by dst) ----------------

__global__ __launch_bounds__(256) void k_hist(const int* __restrict__ dst,
                                              int* __restrict__ cnt) {
    int e = blockIdx.x * 256 + threadIdx.x;
    if (e < NE) atomicAdd(&cnt[dst[e]], 1);
}

// hierarchical scan, stage 1: per-block inclusive scan of 256-elem chunks
__global__ __launch_bounds__(256) void k_scan1(const int* __restrict__ cnt,
                                               int* __restrict__ rowptr,
                                               int* __restrict__ partial) {
    __shared__ int buf[256];
    const int t = threadIdx.x;
    const int i = blockIdx.x * 256 + t;
    int v = (i < NN) ? cnt[i] : 0;
    buf[t] = v;
    __syncthreads();
#pragma unroll
    for (int off = 1; off < 256; off <<= 1) {
        int u = (t >= off) ? buf[t - off] : 0;
        __syncthreads();
        buf[t] += u;
        __syncthreads();
    }
    if (i < NN) rowptr[i + 1] = buf[t];
    if (t == 255) partial[blockIdx.x] = buf[255];
}

// stage 2: single block, exclusive scan of SCAN_B partials
__global__ __launch_bounds__(256) void k_scan2(int* __restrict__ partial) {
    __shared__ int buf[256];
    const int t = threadIdx.x;
    int v = (t < SCAN_B) ? partial[t] : 0;
    buf[t] = v;
    __syncthreads();
#pragma unroll
    for (int off = 1; off < 256; off <<= 1) {
        int u = (t >= off) ? buf[t - off] : 0;
        __syncthreads();
        buf[t] += u;
        __syncthreads();
    }
    if (t < SCAN_B) partial[t] = buf[t] - v;  // exclusive
}

// stage 3: add block offsets, set rowptr[0]
__global__ __launch_bounds__(256) void k_scan3(int* __restrict__ rowptr,
                                               const int* __restrict__ partial) {
    const int i = blockIdx.x * 256 + threadIdx.x;
    if (i < NN) rowptr[i + 1] += partial[blockIdx.x];
    if (i == 0) rowptr[0] = 0;
}

__global__ __launch_bounds__(256) void k_fill(const int* __restrict__ src,
                                              const int* __restrict__ dst,
                                              const int* __restrict__ rowptr,
                                              int* __restrict__ cursor,
                                              int* __restrict__ esrc) {
    int e = blockIdx.x * 256 + threadIdx.x;
    if (e < NE) {
        const int d = dst[e];
        const int pos = atomicAdd(&cursor[d], 1);
        esrc[rowptr[d] + pos] = src[e];
    }
}

// ---------------- aggregation by gather (no atomics) ----------------
__global__ __launch_bounds__(192) void k_agg(const unsigned short* __restrict__ srcmat,
                                             const int* __restrict__ rowptr,
                                             const int* __restrict__ esrc,
                                             unsigned short* __restrict__ dstmat) {
    const int n = blockIdx.x;
    const int c = threadIdx.x * 4;
    const int beg = rowptr[n], end = rowptr[n + 1];
    float4 a = {0.f, 0.f, 0.f, 0.f};
    for (int e = beg; e < end; ++e) {
        const int s = esrc[e];
        const ushort4 v = *(const ushort4*)(srcmat + (size_t)s * KC + DD + c);
        a.x += bf2f(v.x); a.y += bf2f(v.y); a.z += bf2f(v.z); a.w += bf2f(v.w);
    }
    const float inv = (end > beg) ? 1.0f / (float)(end - beg) : 1.0f;
    ushort4 o;
    o.x = f2bf(a.x * inv); o.y = f2bf(a.y * inv);
    o.z = f2bf(a.z * inv); o.w = f2bf(a.w * inv);
    *(ushort4*)(dstmat + (size_t)n * KC + c) = o;
}

// ---------------- GEMM: C[M x 768] = A[M x 1536] * B[768 x 1536]^T + bias ----
// 128x128 tile, double-buffered LDS, prefetch-before-compute, XCD-chunked
// tn-fast mapping (round 1: FETCH 464->116 MB, confirmed).
// Round 2: T2 LDS chunk-XOR swizzle. LDS tile = [128 rows][32 shorts] (64B
// rows); unswizzled fragment reads (row*64 + quad*16 bytes) put the 4
// even-r16 lanes of every 8-lane phase group on ONE 4-bank group -> ~8-way
// conflict (SQ_LDS_BANK_CONFLICT 1.44e7; ~2.9x on the 70us LDS-read floor =
// the whole 229us). Fix per rule #21 (both-sides-or-neither with linear
// global_load_lds): pre-swizzle the GLOBAL source col (chunk c loads cols
// ((c&3)^((c>>3)&3))*8) and XOR the ds_read chunk (quad ^ (r16>>1)&3 --
// lane-constant since wm/i*16 contribute 0 to (row>>1)&3). Any 8 consecutive
// lanes then cover all 32 banks exactly once -> conflict-free.
// Staging pointers hoisted out of K-loop (advance 64B/step) to cut VALU.
// MODE 0: +bias, relu, store bf16 into right half of Acat2
// MODE 1: +bias, store f32 to out
template <int MODE>
__global__ __launch_bounds__(256) void k_gemm(const unsigned short* __restrict__ A,
                                              const unsigned short* __restrict__ B,
                                              const float* __restrict__ bias,
                                              unsigned short* __restrict__ outA,
                                              float* __restrict__ outF) {
    __shared__ alignas(16) unsigned short sA[2][128 * 32];
    __shared__ alignas(16) unsigned short sB[2][128 * 32];
    const int tid = threadIdx.x;
    const int w = tid >> 6, lane = tid & 63;
    const int quad = lane >> 4, r16 = lane & 15;
    const int wm = (w & 1) * 64, wn = (w >> 1) * 64;

    // bijective XCD-aware remap (m204)
    const int nwg = NTM * NTN;
    const int q = nwg >> 3, r = nwg & 7;
    const int xcd = blockIdx.x & 7, slot = blockIdx.x >> 3;
    const int L = (xcd < r ? xcd * (q + 1) : r * (q + 1) + (xcd - r) * q) + slot;
    const int tn = L % NTN;   // fast: 6 consecutive L share one A-tile
    const int tm = L / NTN;
    const int rowBase = tm * 128;

    floatx4 acc[4][4];
#pragma unroll
    for (int i = 0; i < 4; ++i)
#pragma unroll
        for (int j = 0; j < 4; ++j) acc[i][j] = (floatx4){0.f, 0.f, 0.f, 0.f};

    // hoisted staging source pointers; chunk c = c0+lane gets global cols
    // ((c&3)^((c>>3)&3))*8 so the linear LDS write lands pre-swizzled (m173)
    const unsigned short* aP[2];
    const unsigned short* bP[2];
    int c0q[2];
#pragma unroll
    for (int qq = 0; qq < 2; ++qq) {
        const int c0 = (w * 2 + qq) * 64;
        const int c = c0 + lane;
        const int row = c >> 2;
        const int colSwz = ((c & 3) ^ ((c >> 3) & 3)) * 8;
        int gr = rowBase + row; if (gr > NN - 1) gr = NN - 1;  // clamp tail tile
        aP[qq] = A + (size_t)gr * KC + colSwz;
        bP[qq] = B + (size_t)(tn * 128 + row) * KC + colSwz;
        c0q[qq] = c0;
    }

    auto stage = [&](int buf) {
#pragma unroll
        for (int qq = 0; qq < 2; ++qq) {
            gld16(aP[qq], &sA[buf][(size_t)c0q[qq] * 8]);
            gld16(bP[qq], &sB[buf][(size_t)c0q[qq] * 8]);
        }
        aP[0] += 32; aP[1] += 32; bP[0] += 32; bP[1] += 32;  // next K-slice
    };

    // swizzled read chunk: quad ^ (r16>>1)&3, in shorts
    const int qs = (quad ^ ((r16 >> 1) & 3)) * 8;

    auto compute = [&](int buf) {
        bf16x8 af[4], bfr[4];
#pragma unroll
        for (int i = 0; i < 4; ++i)
            af[i] = *(const bf16x8*)(&sA[buf][(wm + i * 16 + r16) * 32 + qs]);
#pragma unroll
        for (int j = 0; j < 4; ++j)
            bfr[j] = *(const bf16x8*)(&sB[buf][(wn + j * 16 + r16) * 32 + qs]);
#pragma unroll
        for (int i = 0; i < 4; ++i)
#pragma unroll
            for (int j = 0; j < 4; ++j)
                acc[i][j] = __builtin_amdgcn_mfma_f32_16x16x32_bf16(af[i], bfr[j], acc[i][j], 0, 0, 0);
    };

    const int nk = KC / 32;  // 48 (even)
    stage(0);
    __syncthreads();  // tile 0 resident

    for (int kt = 0; kt < nk; kt += 2) {
        if (kt + 1 < nk) stage(1);   // prefetch tile kt+1
        compute(0);                  // tile kt
        __syncthreads();
        if (kt + 2 < nk) stage(0);   // prefetch tile kt+2
        compute(1);                  // tile kt+1
        __syncthreads();
    }

    // epilogue: C/D layout col=lane&15, row=quad*4+reg
#pragma unroll
    for (int i = 0; i < 4; ++i)
#pragma unroll
        for (int j = 0; j < 4; ++j) {
            const int gcol = tn * 128 + wn + j * 16 + r16;
            const float bv = bias[gcol];
#pragma unroll
            for (int rr = 0; rr < 4; ++rr) {
                const int grow = rowBase + wm + i * 16 + quad * 4 + rr;
                if (grow < NN) {
                    float v = acc[i][j][rr] + bv;
                    if (MODE == 0) {
                        v = fmaxf(v, 0.0f);
                        outA[(size_t)grow * KC + DD + gcol] = f2bf(v);
                    } else {
                        outF[(size_t)grow * DD + gcol] = v;
                    }
                }
            }
        }
}

extern "C" void kernel_launch(void* const* d_in, const int* in_sizes, int n_in,
                              void* d_out, int out_size, void* d_ws, size_t ws_size,
                              hipStream_t stream) {
    const float* x   = (const float*)d_in[0];
    const int*   ei  = (const int*)d_in[1];
    const float* W1l = (const float*)d_in[2];
    const float* b1l = (const float*)d_in[3];
    const float* W1r = (const float*)d_in[4];
    const float* W2l = (const float*)d_in[5];
    const float* b2l = (const float*)d_in[6];
    const float* W2r = (const float*)d_in[7];
    const int* src = ei;
    const int* dst = ei + NE;
    float* out = (float*)d_out;

    // ws layout (~310 MB):
    //   Acat1: [N x 1536] bf16  (left=agg1, right=bf16(x))
    //   Acat2: [N x 1536] bf16  (left=agg2, right=h)
    //   B1,B2: [768 x 1536] bf16 each
    //   CSR:   cnt[N] (reused as cursor), rowptr[N+1], esrc[E], partial[SCAN_B]
    char* ws = (char*)d_ws;
    unsigned short* Acat1 = (unsigned short*)ws;
    unsigned short* Acat2 = (unsigned short*)(ws + (size_t)NN * KC * 2);
    unsigned short* B1    = (unsigned short*)(ws + (size_t)NN * KC * 4);
    unsigned short* B2    = B1 + (size_t)DD * KC;
    int* cnt    = (int*)(ws + (size_t)NN * KC * 4 + (size_t)DD * KC * 4);
    int* rowptr = cnt + NN;
    int* esrc   = rowptr + NN + 1;
    int* partial = esrc + NE;

    // CSR build (hierarchical scan; no single-block serialization)
    hipMemsetAsync(cnt, 0, NN * sizeof(int), stream);
    k_hist<<<(NE + 255) / 256, 256, 0, stream>>>(dst, cnt);
    k_scan1<<<SCAN_B, 256, 0, stream>>>(cnt, rowptr, partial);
    k_scan2<<<1, 256, 0, stream>>>(partial);
    k_scan3<<<SCAN_B, 256, 0, stream>>>(rowptr, partial);
    hipMemsetAsync(cnt, 0, NN * sizeof(int), stream);  // reuse as cursor
    k_fill<<<(NE + 255) / 256, 256, 0, stream>>>(src, dst, rowptr, cnt, esrc);

    // converts
    k_convert_x<<<NN, 192, 0, stream>>>(x, Acat1);
    dim3 wgrid(DD, 2);
    k_convert_w<<<wgrid, 384, 0, stream>>>(W1l, W1r, W2l, W2r, B1, B2);

    const int ggrid = NTM * NTN;  // 1D grid, XCD-chunked tn-fast mapping inside kernel

    // layer 1 (aggregate bf16(x) from right half of Acat1)
    k_agg<<<NN, 192, 0, stream>>>(Acat1, rowptr, esrc, Acat1);
    k_gemm<0><<<ggrid, 256, 0, stream>>>(Acat1, B1, b1l, Acat2, nullptr);

    // layer 2
    k_agg<<<NN, 192, 0, stream>>>(Acat2, rowptr, esrc, Acat2);
    k_gemm<1><<<ggrid, 256, 0, stream>>>(Acat2, B2, b2l, nullptr, out);
}

// Round 5
// 795.843 us; speedup vs baseline: 1.0089x; 1.0089x over previous
//
#include <hip/hip_runtime.h>
#include <stdint.h>

#define NN 50000   // nodes
#define NE 100000  // edges
#define DD 768     // feature dim
#define KC 1536    // concatenated K = 2*DD
#define SCAN_B 196 // ceil(NN/256)
#define NTM 391    // ceil(NN/128)
#define NTN 6      // DD/128

typedef __attribute__((ext_vector_type(8))) __bf16 bf16x8;
typedef __attribute__((ext_vector_type(4))) float floatx4;

static __device__ __forceinline__ float bf2f(unsigned short u) {
    union { unsigned int u; float f; } c; c.u = ((unsigned int)u) << 16; return c.f;
}
static __device__ __forceinline__ unsigned short f2bf(float f) {
    union { float f; unsigned int u; } c; c.f = f;
    return (unsigned short)((c.u + 0x7FFFu + ((c.u >> 16) & 1u)) >> 16);
}

// async global->LDS, 16B per lane; LDS dst = wave-uniform base + lane*16
static __device__ __forceinline__ void gld16(const void* g, void* l) {
    __builtin_amdgcn_global_load_lds(
        (const __attribute__((address_space(1))) unsigned int*)g,
        (__attribute__((address_space(3))) unsigned int*)l, 16, 0, 0);
}

// ---------------- prep kernels ----------------

// x (f32) -> bf16 into right half of Acat1 ([n][768..1535])
__global__ __launch_bounds__(192) void k_convert_x(const float* __restrict__ x,
                                                   unsigned short* __restrict__ acat) {
    const int n = blockIdx.x;
    const int c = threadIdx.x * 4;
    const float4 v = *(const float4*)(x + (size_t)n * DD + c);
    ushort4 o;
    o.x = f2bf(v.x); o.y = f2bf(v.y); o.z = f2bf(v.z); o.w = f2bf(v.w);
    *(ushort4*)(acat + (size_t)n * KC + DD + c) = o;
}

// Bcat[layer][j][k] = k<768 ? Wl[j][k] : Wr[j][k-768]   (bf16)
__global__ __launch_bounds__(384) void k_convert_w(const float* __restrict__ W1l,
                                                   const float* __restrict__ W1r,
                                                   const float* __restrict__ W2l,
                                                   const float* __restrict__ W2r,
                                                   unsigned short* __restrict__ B1,
                                                   unsigned short* __restrict__ B2) {
    const int j = blockIdx.x;
    const int layer = blockIdx.y;
    const int k = threadIdx.x * 4;
    const float* Wl = layer ? W2l : W1l;
    const float* Wr = layer ? W2r : W1r;
    unsigned short* B = layer ? B2 : B1;
    const float4 v = (k < DD) ? *(const float4*)(Wl + (size_t)j * DD + k)
                              : *(const float4*)(Wr + (size_t)j * DD + (k - DD));
    ushort4 o; o.x = f2bf(v.x); o.y = f2bf(v.y); o.z = f2bf(v.z); o.w = f2bf(v.w);
    *(ushort4*)(B + (size_t)j * KC + k) = o;
}

// ---------------- CSR build (by dst) ----------------

__global__ __launch_bounds__(256) void k_hist(const int* __restrict__ dst,
                                              int* __restrict__ cnt) {
    int e = blockIdx.x * 256 + threadIdx.x;
    if (e < NE) atomicAdd(&cnt[dst[e]], 1);
}

// hierarchical scan, stage 1: per-block inclusive scan of 256-elem chunks
__global__ __launch_bounds__(256) void k_scan1(const int* __restrict__ cnt,
                                               int* __restrict__ rowptr,
                                               int* __restrict__ partial) {
    __shared__ int buf[256];
    const int t = threadIdx.x;
    const int i = blockIdx.x * 256 + t;
    int v = (i < NN) ? cnt[i] : 0;
    buf[t] = v;
    __syncthreads();
#pragma unroll
    for (int off = 1; off < 256; off <<= 1) {
        int u = (t >= off) ? buf[t - off] : 0;
        __syncthreads();
        buf[t] += u;
        __syncthreads();
    }
    if (i < NN) rowptr[i + 1] = buf[t];
    if (t == 255) partial[blockIdx.x] = buf[255];
}

// stage 2: single block, exclusive scan of SCAN_B partials
__global__ __launch_bounds__(256) void k_scan2(int* __restrict__ partial) {
    __shared__ int buf[256];
    const int t = threadIdx.x;
    int v = (t < SCAN_B) ? partial[t] : 0;
    buf[t] = v;
    __syncthreads();
#pragma unroll
    for (int off = 1; off < 256; off <<= 1) {
        int u = (t >= off) ? buf[t - off] : 0;
        __syncthreads();
        buf[t] += u;
        __syncthreads();
    }
    if (t < SCAN_B) partial[t] = buf[t] - v;  // exclusive
}

// stage 3: add block offsets, set rowptr[0]
__global__ __launch_bounds__(256) void k_scan3(int* __restrict__ rowptr,
                                               const int* __restrict__ partial) {
    const int i = blockIdx.x * 256 + threadIdx.x;
    if (i < NN) rowptr[i + 1] += partial[blockIdx.x];
    if (i == 0) rowptr[0] = 0;
}

__global__ __launch_bounds__(256) void k_fill(const int* __restrict__ src,
                                              const int* __restrict__ dst,
                                              const int* __restrict__ rowptr,
                                              int* __restrict__ cursor,
                                              int* __restrict__ esrc) {
    int e = blockIdx.x * 256 + threadIdx.x;
    if (e < NE) {
        const int d = dst[e];
        const int pos = atomicAdd(&cursor[d], 1);
        esrc[rowptr[d] + pos] = src[e];
    }
}

// ---------------- aggregation by gather (no atomics) ----------------
__global__ __launch_bounds__(192) void k_agg(const unsigned short* __restrict__ srcmat,
                                             const int* __restrict__ rowptr,
                                             const int* __restrict__ esrc,
                                             unsigned short* __restrict__ dstmat) {
    const int n = blockIdx.x;
    const int c = threadIdx.x * 4;
    const int beg = rowptr[n], end = rowptr[n + 1];
    float4 a = {0.f, 0.f, 0.f, 0.f};
    for (int e = beg; e < end; ++e) {
        const int s = esrc[e];
        const ushort4 v = *(const ushort4*)(srcmat + (size_t)s * KC + DD + c);
        a.x += bf2f(v.x); a.y += bf2f(v.y); a.z += bf2f(v.z); a.w += bf2f(v.w);
    }
    const float inv = (end > beg) ? 1.0f / (float)(end - beg) : 1.0f;
    ushort4 o;
    o.x = f2bf(a.x * inv); o.y = f2bf(a.y * inv);
    o.z = f2bf(a.z * inv); o.w = f2bf(a.w * inv);
    *(ushort4*)(dstmat + (size_t)n * KC + c) = o;
}

// ---------------- GEMM: C[M x 768] = A[M x 1536] * B[768 x 1536]^T + bias ----
// Round 5 = round 3 kernel, resubmitted again (r3: container failed twice,
// r4: GPU acquisition timeout — source never reached a chip either time).
// Theory: T4 counted-vmcnt pipeline. History: r0 464MB fetch fixed by XCD
// map (r1, FETCH->116MB, no speedup); LDS conflicts 1.44e7 fixed by chunk-XOR
// swizzle (r2, ->0, no speedup); MfmaUtil pinned ~21% throughout => bottleneck
// is the __syncthreads() vmcnt(0) drain exposing ~700cy HBM latency per
// K-step (A streams from HBM). Fix: triple-buffered LDS (48KB), depth-2
// prefetch, raw s_barrier + s_waitcnt vmcnt(4) (NEVER 0 in main loop) so the
// next tile's 4 loads stay in flight ACROSS the barrier. Fully static buffer
// indices; sched_barrier(0) fences per rule #18. 48KB LDS -> 3 blocks/CU.
// T5 setprio around MFMA cluster (blocks mutually async = role diversity).
// MODE 0: +bias, relu, store bf16 into right half of Acat2
// MODE 1: +bias, store f32 to out
template <int MODE>
__global__ __launch_bounds__(256) void k_gemm(const unsigned short* __restrict__ A,
                                              const unsigned short* __restrict__ B,
                                              const float* __restrict__ bias,
                                              unsigned short* __restrict__ outA,
                                              float* __restrict__ outF) {
    __shared__ alignas(16) unsigned short sA[3][128 * 32];
    __shared__ alignas(16) unsigned short sB[3][128 * 32];
    const int tid = threadIdx.x;
    const int w = tid >> 6, lane = tid & 63;
    const int quad = lane >> 4, r16 = lane & 15;
    const int wm = (w & 1) * 64, wn = (w >> 1) * 64;

    // bijective XCD-aware remap (m204)
    const int nwg = NTM * NTN;
    const int q = nwg >> 3, r = nwg & 7;
    const int xcd = blockIdx.x & 7, slot = blockIdx.x >> 3;
    const int L = (xcd < r ? xcd * (q + 1) : r * (q + 1) + (xcd - r) * q) + slot;
    const int tn = L % NTN;   // fast: 6 consecutive L share one A-tile
    const int tm = L / NTN;
    const int rowBase = tm * 128;

    floatx4 acc[4][4];
#pragma unroll
    for (int i = 0; i < 4; ++i)
#pragma unroll
        for (int j = 0; j < 4; ++j) acc[i][j] = (floatx4){0.f, 0.f, 0.f, 0.f};

    // hoisted staging source pointers; chunk c = c0+lane gets global cols
    // ((c&3)^((c>>3)&3))*8 so the linear LDS write lands pre-swizzled (m173)
    const unsigned short* aP[2];
    const unsigned short* bP[2];
    int c0q[2];
#pragma unroll
    for (int qq = 0; qq < 2; ++qq) {
        const int c0 = (w * 2 + qq) * 64;
        const int c = c0 + lane;
        const int row = c >> 2;
        const int colSwz = ((c & 3) ^ ((c >> 3) & 3)) * 8;
        int gr = rowBase + row; if (gr > NN - 1) gr = NN - 1;  // clamp tail tile
        aP[qq] = A + (size_t)gr * KC + colSwz;
        bP[qq] = B + (size_t)(tn * 128 + row) * KC + colSwz;
        c0q[qq] = c0;
    }

    // each call issues exactly 4 gld16 per lane (A,B x 2 chunks) = one tile
    auto stage = [&](int buf) {
#pragma unroll
        for (int qq = 0; qq < 2; ++qq) {
            gld16(aP[qq], &sA[buf][(size_t)c0q[qq] * 8]);
            gld16(bP[qq], &sB[buf][(size_t)c0q[qq] * 8]);
        }
        aP[0] += 32; aP[1] += 32; bP[0] += 32; bP[1] += 32;  // next K-slice
    };

    // swizzled read chunk: quad ^ (r16>>1)&3, in shorts
    const int qs = (quad ^ ((r16 >> 1) & 3)) * 8;

    auto compute = [&](int buf) {
        bf16x8 af[4], bfr[4];
#pragma unroll
        for (int i = 0; i < 4; ++i)
            af[i] = *(const bf16x8*)(&sA[buf][(wm + i * 16 + r16) * 32 + qs]);
#pragma unroll
        for (int j = 0; j < 4; ++j)
            bfr[j] = *(const bf16x8*)(&sB[buf][(wn + j * 16 + r16) * 32 + qs]);
        __builtin_amdgcn_s_setprio(1);
#pragma unroll
        for (int i = 0; i < 4; ++i)
#pragma unroll
            for (int j = 0; j < 4; ++j)
                acc[i][j] = __builtin_amdgcn_mfma_f32_16x16x32_bf16(af[i], bfr[j], acc[i][j], 0, 0, 0);
        __builtin_amdgcn_s_setprio(0);
    };

    // counted wait + raw barrier: only the tile about to be computed is
    // drained; the in-flight tile's 4 loads survive the barrier (T4).
#define WAITB(N)                                          \
    do {                                                  \
        __builtin_amdgcn_sched_barrier(0);                \
        asm volatile("s_waitcnt vmcnt(" #N ")" ::: "memory"); \
        __builtin_amdgcn_s_barrier();                     \
        __builtin_amdgcn_sched_barrier(0);                \
    } while (0)

    // tile t lives in buffer t%3.  nk = 48 = 16 groups of 3.
    stage(0);  // tile 0
    stage(1);  // tile 1   (8 loads in flight)
    for (int g = 0; g < 15; ++g) {
        // kt=3g:   wait tile kt (vmcnt 8->4), stage tile kt+2 -> buf 2
        WAITB(4); stage(2); compute(0);
        // kt=3g+1: stage tile kt+2 -> buf 0
        WAITB(4); stage(0); compute(1);
        // kt=3g+2: stage tile kt+2 -> buf 1
        WAITB(4); stage(1); compute(2);
    }
    // peeled tail: kt = 45, 46, 47
    WAITB(4); stage(2); compute(0);  // kt=45: stage tile 47 -> buf 2
    WAITB(4); compute(1);            // kt=46: wait tile 46
    WAITB(0); compute(2);            // kt=47: drain last tile
#undef WAITB

    // epilogue: C/D layout col=lane&15, row=quad*4+reg
#pragma unroll
    for (int i = 0; i < 4; ++i)
#pragma unroll
        for (int j = 0; j < 4; ++j) {
            const int gcol = tn * 128 + wn + j * 16 + r16;
            const float bv = bias[gcol];
#pragma unroll
            for (int rr = 0; rr < 4; ++rr) {
                const int grow = rowBase + wm + i * 16 + quad * 4 + rr;
                if (grow < NN) {
                    float v = acc[i][j][rr] + bv;
                    if (MODE == 0) {
                        v = fmaxf(v, 0.0f);
                        outA[(size_t)grow * KC + DD + gcol] = f2bf(v);
                    } else {
                        outF[(size_t)grow * DD + gcol] = v;
                    }
                }
            }
        }
}

extern "C" void kernel_launch(void* const* d_in, const int* in_sizes, int n_in,
                              void* d_out, int out_size, void* d_ws, size_t ws_size,
                              hipStream_t stream) {
    const float* x   = (const float*)d_in[0];
    const int*   ei  = (const int*)d_in[1];
    const float* W1l = (const float*)d_in[2];
    const float* b1l = (const float*)d_in[3];
    const float* W1r = (const float*)d_in[4];
    const float* W2l = (const float*)d_in[5];
    const float* b2l = (const float*)d_in[6];
    const float* W2r = (const float*)d_in[7];
    const int* src = ei;
    const int* dst = ei + NE;
    float* out = (float*)d_out;

    // ws layout (~310 MB):
    //   Acat1: [N x 1536] bf16  (left=agg1, right=bf16(x))
    //   Acat2: [N x 1536] bf16  (left=agg2, right=h)
    //   B1,B2: [768 x 1536] bf16 each
    //   CSR:   cnt[N] (reused as cursor), rowptr[N+1], esrc[E], partial[SCAN_B]
    char* ws = (char*)d_ws;
    unsigned short* Acat1 = (unsigned short*)ws;
    unsigned short* Acat2 = (unsigned short*)(ws + (size_t)NN * KC * 2);
    unsigned short* B1    = (unsigned short*)(ws + (size_t)NN * KC * 4);
    unsigned short* B2    = B1 + (size_t)DD * KC;
    int* cnt    = (int*)(ws + (size_t)NN * KC * 4 + (size_t)DD * KC * 4);
    int* rowptr = cnt + NN;
    int* esrc   = rowptr + NN + 1;
    int* partial = esrc + NE;

    // CSR build (hierarchical scan; no single-block serialization)
    hipMemsetAsync(cnt, 0, NN * sizeof(int), stream);
    k_hist<<<(NE + 255) / 256, 256, 0, stream>>>(dst, cnt);
    k_scan1<<<SCAN_B, 256, 0, stream>>>(cnt, rowptr, partial);
    k_scan2<<<1, 256, 0, stream>>>(partial);
    k_scan3<<<SCAN_B, 256, 0, stream>>>(rowptr, partial);
    hipMemsetAsync(cnt, 0, NN * sizeof(int), stream);  // reuse as cursor
    k_fill<<<(NE + 255) / 256, 256, 0, stream>>>(src, dst, rowptr, cnt, esrc);

    // converts
    k_convert_x<<<NN, 192, 0, stream>>>(x, Acat1);
    dim3 wgrid(DD, 2);
    k_convert_w<<<wgrid, 384, 0, stream>>>(W1l, W1r, W2l, W2r, B1, B2);

    const int ggrid = NTM * NTN;  // 1D grid, XCD-chunked tn-fast mapping inside kernel

    // layer 1 (aggregate bf16(x) from right half of Acat1)
    k_agg<<<NN, 192, 0, stream>>>(Acat1, rowptr, esrc, Acat1);
    k_gemm<0><<<ggrid, 256, 0, stream>>>(Acat1, B1, b1l, Acat2, nullptr);

    // layer 2
    k_agg<<<NN, 192, 0, stream>>>(Acat2, rowptr, esrc, Acat2);
    k_gemm<1><<<ggrid, 256, 0, stream>>>(Acat2, B2, b2l, nullptr, out);
}

// Round 6
// 727.275 us; speedup vs baseline: 1.1040x; 1.0943x over previous
//
#include <hip/hip_runtime.h>
#include <stdint.h>

#define NN 50000   // nodes
#define NE 100000  // edges
#define DD 768     // feature dim
#define KC 1536    // concatenated K = 2*DD
#define SCAN_B 196 // ceil(NN/256)
#define BM 128
#define BN 256
#define BK 64
#define NTM 391    // ceil(NN/128)
#define NTN 3      // DD/256

typedef __attribute__((ext_vector_type(8))) __bf16 bf16x8;
typedef __attribute__((ext_vector_type(4))) float floatx4;

static __device__ __forceinline__ float bf2f(unsigned short u) {
    union { unsigned int u; float f; } c; c.u = ((unsigned int)u) << 16; return c.f;
}
static __device__ __forceinline__ unsigned short f2bf(float f) {
    union { float f; unsigned int u; } c; c.f = f;
    return (unsigned short)((c.u + 0x7FFFu + ((c.u >> 16) & 1u)) >> 16);
}

// async global->LDS, 16B per lane; LDS dst = wave-uniform base + lane*16
static __device__ __forceinline__ void gld16(const void* g, void* l) {
    __builtin_amdgcn_global_load_lds(
        (const __attribute__((address_space(1))) unsigned int*)g,
        (__attribute__((address_space(3))) unsigned int*)l, 16, 0, 0);
}

// ---------------- prep kernels ----------------

// x (f32) -> bf16 into right half of Acat1 ([n][768..1535])
__global__ __launch_bounds__(192) void k_convert_x(const float* __restrict__ x,
                                                   unsigned short* __restrict__ acat) {
    const int n = blockIdx.x;
    const int c = threadIdx.x * 4;
    const float4 v = *(const float4*)(x + (size_t)n * DD + c);
    ushort4 o;
    o.x = f2bf(v.x); o.y = f2bf(v.y); o.z = f2bf(v.z); o.w = f2bf(v.w);
    *(ushort4*)(acat + (size_t)n * KC + DD + c) = o;
}

// Bcat[layer][j][k] = k<768 ? Wl[j][k] : Wr[j][k-768]   (bf16)
__global__ __launch_bounds__(384) void k_convert_w(const float* __restrict__ W1l,
                                                   const float* __restrict__ W1r,
                                                   const float* __restrict__ W2l,
                                                   const float* __restrict__ W2r,
                                                   unsigned short* __restrict__ B1,
                                                   unsigned short* __restrict__ B2) {
    const int j = blockIdx.x;
    const int layer = blockIdx.y;
    const int k = threadIdx.x * 4;
    const float* Wl = layer ? W2l : W1l;
    const float* Wr = layer ? W2r : W1r;
    unsigned short* B = layer ? B2 : B1;
    const float4 v = (k < DD) ? *(const float4*)(Wl + (size_t)j * DD + k)
                              : *(const float4*)(Wr + (size_t)j * DD + (k - DD));
    ushort4 o; o.x = f2bf(v.x); o.y = f2bf(v.y); o.z = f2bf(v.z); o.w = f2bf(v.w);
    *(ushort4*)(B + (size_t)j * KC + k) = o;
}

// ---------------- CSR build (by dst) ----------------

__global__ __launch_bounds__(256) void k_hist(const int* __restrict__ dst,
                                              int* __restrict__ cnt) {
    int e = blockIdx.x * 256 + threadIdx.x;
    if (e < NE) atomicAdd(&cnt[dst[e]], 1);
}

// hierarchical scan, stage 1: per-block inclusive scan of 256-elem chunks
__global__ __launch_bounds__(256) void k_scan1(const int* __restrict__ cnt,
                                               int* __restrict__ rowptr,
                                               int* __restrict__ partial) {
    __shared__ int buf[256];
    const int t = threadIdx.x;
    const int i = blockIdx.x * 256 + t;
    int v = (i < NN) ? cnt[i] : 0;
    buf[t] = v;
    __syncthreads();
#pragma unroll
    for (int off = 1; off < 256; off <<= 1) {
        int u = (t >= off) ? buf[t - off] : 0;
        __syncthreads();
        buf[t] += u;
        __syncthreads();
    }
    if (i < NN) rowptr[i + 1] = buf[t];
    if (t == 255) partial[blockIdx.x] = buf[255];
}

// stage 2: single block, exclusive scan of SCAN_B partials
__global__ __launch_bounds__(256) void k_scan2(int* __restrict__ partial) {
    __shared__ int buf[256];
    const int t = threadIdx.x;
    int v = (t < SCAN_B) ? partial[t] : 0;
    buf[t] = v;
    __syncthreads();
#pragma unroll
    for (int off = 1; off < 256; off <<= 1) {
        int u = (t >= off) ? buf[t - off] : 0;
        __syncthreads();
        buf[t] += u;
        __syncthreads();
    }
    if (t < SCAN_B) partial[t] = buf[t] - v;  // exclusive
}

// stage 3: add block offsets, set rowptr[0]
__global__ __launch_bounds__(256) void k_scan3(int* __restrict__ rowptr,
                                               const int* __restrict__ partial) {
    const int i = blockIdx.x * 256 + threadIdx.x;
    if (i < NN) rowptr[i + 1] += partial[blockIdx.x];
    if (i == 0) rowptr[0] = 0;
}

__global__ __launch_bounds__(256) void k_fill(const int* __restrict__ src,
                                              const int* __restrict__ dst,
                                              const int* __restrict__ rowptr,
                                              int* __restrict__ cursor,
                                              int* __restrict__ esrc) {
    int e = blockIdx.x * 256 + threadIdx.x;
    if (e < NE) {
        const int d = dst[e];
        const int pos = atomicAdd(&cursor[d], 1);
        esrc[rowptr[d] + pos] = src[e];
    }
}

// ---------------- aggregation by gather (no atomics) ----------------
__global__ __launch_bounds__(192) void k_agg(const unsigned short* __restrict__ srcmat,
                                             const int* __restrict__ rowptr,
                                             const int* __restrict__ esrc,
                                             unsigned short* __restrict__ dstmat) {
    const int n = blockIdx.x;
    const int c = threadIdx.x * 4;
    const int beg = rowptr[n], end = rowptr[n + 1];
    float4 a = {0.f, 0.f, 0.f, 0.f};
    for (int e = beg; e < end; ++e) {
        const int s = esrc[e];
        const ushort4 v = *(const ushort4*)(srcmat + (size_t)s * KC + DD + c);
        a.x += bf2f(v.x); a.y += bf2f(v.y); a.z += bf2f(v.z); a.w += bf2f(v.w);
    }
    const float inv = (end > beg) ? 1.0f / (float)(end - beg) : 1.0f;
    ushort4 o;
    o.x = f2bf(a.x * inv); o.y = f2bf(a.y * inv);
    o.z = f2bf(a.z * inv); o.w = f2bf(a.w * inv);
    *(ushort4*)(dstmat + (size_t)n * KC + c) = o;
}

// ---------------- GEMM: C[M x 768] = A[M x 1536] * B[768 x 1536]^T + bias ----
// Round 6: phase-interleaved template (T3+T4, enabling T2+T5). r1-r5 grafted
// T1/T2/T4/T5 onto the 2-phase/2-barrier K-step structure: every fix landed
// on its own counter (FETCH 464->116MB, conflicts 1.44e7->0, VALU 34->17%)
// and NONE moved time; MfmaUtil pinned 20.5-21%. Catalog regime-gate says
// exactly this: T2/T5 NULL on 2-phase; 2-phase stall = stage+vmcnt+barrier
// (m233: 72%); escape = phase-interleaved schedule with 8 waves.
// New structure: BM=128 BN=256 BK=64, 512 threads = 8 waves (2M x 4N),
// wave-tile 64x64 (per-phase compute identical to the old verified K-step:
// 8 ds_read_b128 + 16 MFMA). 3 LDS K-tile slots (144KB): slot = t%3,
// staging for tile t+2 issued during tile t -> never writes a slot being
// read this or next tile (structural race-freedom). Counted s_waitcnt
// vmcnt(6) at K-tile boundaries ONLY (next-next tile's 6 loads stay in
// flight across the barrier; never 0 mid-loop). Per phase: {reads + 3
// gld16 -> barrier -> setprio(1) 16 MFMA setprio(0) -> [vmcnt] -> barrier}.
// Chunk-XOR swizzle kept (re-derived for [.][64] rows): LDS slot (row,j)
// holds global col-chunk j^(row&7); read phys = (ksub*4+quad)^(r16&7);
// 2 lanes/bank = conflict-free.
// MODE 0: +bias, relu, store bf16 into right half of Acat2
// MODE 1: +bias, store f32 to out
template <int MODE>
__global__ __launch_bounds__(512) void k_gemm(const unsigned short* __restrict__ A,
                                              const unsigned short* __restrict__ B,
                                              const float* __restrict__ bias,
                                              unsigned short* __restrict__ outA,
                                              float* __restrict__ outF) {
    // 3 K-tile slots: A 128x64 (16KB) + B 256x64 (32KB) each -> 144KB total
    __shared__ alignas(16) unsigned short sA[3][BM * BK];
    __shared__ alignas(16) unsigned short sB[3][BN * BK];
    const int tid = threadIdx.x;
    const int w = tid >> 6, lane = tid & 63;
    const int quad = lane >> 4, r16 = lane & 15;
    const int wr = w >> 2, wc = w & 3;      // 2M x 4N wave grid
    const int wm = wr * 64, wn = wc * 64;   // wave-tile 64x64

    // bijective XCD-aware remap (m204); tn fast (3 blocks share one A-panel)
    const int nwg = NTM * NTN;              // 1173, %8 = 5
    const int q = nwg >> 3, r = nwg & 7;
    const int xcd = blockIdx.x & 7, slot = blockIdx.x >> 3;
    const int L = (xcd < r ? xcd * (q + 1) : r * (q + 1) + (xcd - r) * q) + slot;
    const int tn = L % NTN;
    const int tm = L / NTN;
    const int rowBase = tm * BM;

    floatx4 acc[4][4];
#pragma unroll
    for (int i = 0; i < 4; ++i)
#pragma unroll
        for (int j = 0; j < 4; ++j) acc[i][j] = (floatx4){0.f, 0.f, 0.f, 0.f};

    // staging source pointers, pre-swizzled (m173): chunk c = l*512+tid,
    // row = c>>3, physical col-chunk (c&7) receives global chunk (c&7)^(row&7)
    const unsigned short* aS[2];
    const unsigned short* bS[4];
#pragma unroll
    for (int l = 0; l < 2; ++l) {
        const int c = l * 512 + tid;
        const int row = c >> 3;
        const int jd = ((c & 7) ^ (row & 7)) * 8;
        int gr = rowBase + row; if (gr > NN - 1) gr = NN - 1;  // clamp tail tile
        aS[l] = A + (size_t)gr * KC + jd;
    }
#pragma unroll
    for (int l = 0; l < 4; ++l) {
        const int c = l * 512 + tid;
        const int row = c >> 3;
        const int jd = ((c & 7) ^ (row & 7)) * 8;
        bS[l] = B + (size_t)(tn * BN + row) * KC + jd;
    }

    // stage half of K-tile into slot d. half 0: A l=0,1 + B l=0 (3 loads);
    // half 1: B l=1,2,3 (3 loads) + pointer advance. 6 loads per K-tile.
    auto stageK = [&](int d, int half) {
        if (half == 0) {
            gld16(aS[0], &sA[d][(0 * 512 + w * 64) * 8]);
            gld16(aS[1], &sA[d][(1 * 512 + w * 64) * 8]);
            gld16(bS[0], &sB[d][(0 * 512 + w * 64) * 8]);
        } else {
            gld16(bS[1], &sB[d][(1 * 512 + w * 64) * 8]);
            gld16(bS[2], &sB[d][(2 * 512 + w * 64) * 8]);
            gld16(bS[3], &sB[d][(3 * 512 + w * 64) * 8]);
            aS[0] += BK; aS[1] += BK;
            bS[0] += BK; bS[1] += BK; bS[2] += BK; bS[3] += BK;
        }
    };

    // one phase = one K-sub-step (ksub = p): reads + stage, barrier, MFMA.
    // Caller appends [vmcnt] + trailing barrier.
    auto phase = [&](int s, int p, int d, int doStage) {
        const int physc = ((p * 4 + quad) ^ (r16 & 7)) * 8;  // swizzled chunk (shorts)
        bf16x8 af[4], bfr[4];
#pragma unroll
        for (int mf = 0; mf < 4; ++mf)
            af[mf] = *(const bf16x8*)(&sA[s][(wm + mf * 16 + r16) * BK + physc]);
#pragma unroll
        for (int nf = 0; nf < 4; ++nf)
            bfr[nf] = *(const bf16x8*)(&sB[s][(wn + nf * 16 + r16) * BK + physc]);
        if (doStage) stageK(d, p);
        __builtin_amdgcn_sched_barrier(0);
        __builtin_amdgcn_s_barrier();
        __builtin_amdgcn_sched_barrier(0);
        __builtin_amdgcn_s_setprio(1);
#pragma unroll
        for (int mf = 0; mf < 4; ++mf)
#pragma unroll
            for (int nf = 0; nf < 4; ++nf)
                acc[mf][nf] = __builtin_amdgcn_mfma_f32_16x16x32_bf16(af[mf], bfr[nf], acc[mf][nf], 0, 0, 0);
        __builtin_amdgcn_s_setprio(0);
        __builtin_amdgcn_sched_barrier(0);
    };

#define SB                                            \
    do {                                              \
        __builtin_amdgcn_s_barrier();                 \
        __builtin_amdgcn_sched_barrier(0);            \
    } while (0)
#define VW(N)                                             \
    do {                                                  \
        __builtin_amdgcn_sched_barrier(0);                \
        asm volatile("s_waitcnt vmcnt(" #N ")" ::: "memory"); \
    } while (0)

    // prologue: K-tiles 0,1 staged (12 loads); wait tile 0 (6 left in flight)
    stageK(0, 0); stageK(0, 1);
    stageK(1, 0); stageK(1, 1);
    VW(6);
    SB;

    // 24 K-tiles, slot = t%3, staging targets slot (t+2)%3.
    // t = 0..20 (7 groups of 3, staging tiles 2..22):
#pragma unroll 1
    for (int g = 0; g < 7; ++g) {
        phase(0, 0, 2, 1); SB; phase(0, 1, 2, 1); VW(6); SB;
        phase(1, 0, 0, 1); SB; phase(1, 1, 0, 1); VW(6); SB;
        phase(2, 0, 1, 1); SB; phase(2, 1, 1, 1); VW(6); SB;
    }
    // t=21 (slot 0): stages tile 23 -> slot 2
    phase(0, 0, 2, 1); SB; phase(0, 1, 2, 1); VW(6); SB;
    // t=22 (slot 1): no staging; drain so tile 23 is resident
    phase(1, 0, 0, 0); SB; phase(1, 1, 0, 0); VW(0); SB;
    // t=23 (slot 2): final tile
    phase(2, 0, 0, 0); SB; phase(2, 1, 0, 0);
#undef SB
#undef VW

    // epilogue: C/D layout col=lane&15, row=quad*4+reg
#pragma unroll
    for (int mf = 0; mf < 4; ++mf)
#pragma unroll
        for (int nf = 0; nf < 4; ++nf) {
            const int gcol = tn * BN + wn + nf * 16 + r16;
            const float bv = bias[gcol];
#pragma unroll
            for (int rr = 0; rr < 4; ++rr) {
                const int grow = rowBase + wm + mf * 16 + quad * 4 + rr;
                if (grow < NN) {
                    float v = acc[mf][nf][rr] + bv;
                    if (MODE == 0) {
                        v = fmaxf(v, 0.0f);
                        outA[(size_t)grow * KC + DD + gcol] = f2bf(v);
                    } else {
                        outF[(size_t)grow * DD + gcol] = v;
                    }
                }
            }
        }
}

extern "C" void kernel_launch(void* const* d_in, const int* in_sizes, int n_in,
                              void* d_out, int out_size, void* d_ws, size_t ws_size,
                              hipStream_t stream) {
    const float* x   = (const float*)d_in[0];
    const int*   ei  = (const int*)d_in[1];
    const float* W1l = (const float*)d_in[2];
    const float* b1l = (const float*)d_in[3];
    const float* W1r = (const float*)d_in[4];
    const float* W2l = (const float*)d_in[5];
    const float* b2l = (const float*)d_in[6];
    const float* W2r = (const float*)d_in[7];
    const int* src = ei;
    const int* dst = ei + NE;
    float* out = (float*)d_out;

    // ws layout (~310 MB):
    //   Acat1: [N x 1536] bf16  (left=agg1, right=bf16(x))
    //   Acat2: [N x 1536] bf16  (left=agg2, right=h)
    //   B1,B2: [768 x 1536] bf16 each
    //   CSR:   cnt[N] (reused as cursor), rowptr[N+1], esrc[E], partial[SCAN_B]
    char* ws = (char*)d_ws;
    unsigned short* Acat1 = (unsigned short*)ws;
    unsigned short* Acat2 = (unsigned short*)(ws + (size_t)NN * KC * 2);
    unsigned short* B1    = (unsigned short*)(ws + (size_t)NN * KC * 4);
    unsigned short* B2    = B1 + (size_t)DD * KC;
    int* cnt    = (int*)(ws + (size_t)NN * KC * 4 + (size_t)DD * KC * 4);
    int* rowptr = cnt + NN;
    int* esrc   = rowptr + NN + 1;
    int* partial = esrc + NE;

    // CSR build (hierarchical scan; no single-block serialization)
    hipMemsetAsync(cnt, 0, NN * sizeof(int), stream);
    k_hist<<<(NE + 255) / 256, 256, 0, stream>>>(dst, cnt);
    k_scan1<<<SCAN_B, 256, 0, stream>>>(cnt, rowptr, partial);
    k_scan2<<<1, 256, 0, stream>>>(partial);
    k_scan3<<<SCAN_B, 256, 0, stream>>>(rowptr, partial);
    hipMemsetAsync(cnt, 0, NN * sizeof(int), stream);  // reuse as cursor
    k_fill<<<(NE + 255) / 256, 256, 0, stream>>>(src, dst, rowptr, cnt, esrc);

    // converts
    k_convert_x<<<NN, 192, 0, stream>>>(x, Acat1);
    dim3 wgrid(DD, 2);
    k_convert_w<<<wgrid, 384, 0, stream>>>(W1l, W1r, W2l, W2r, B1, B2);

    const int ggrid = NTM * NTN;  // 1173 blocks, XCD-chunked tn-fast mapping inside

    // layer 1 (aggregate bf16(x) from right half of Acat1)
    k_agg<<<NN, 192, 0, stream>>>(Acat1, rowptr, esrc, Acat1);
    k_gemm<0><<<ggrid, 512, 0, stream>>>(Acat1, B1, b1l, Acat2, nullptr);

    // layer 2
    k_agg<<<NN, 192, 0, stream>>>(Acat2, rowptr, esrc, Acat2);
    k_gemm<1><<<ggrid, 512, 0, stream>>>(Acat2, B2, b2l, nullptr, out);
}

// Round 7
// 705.545 us; speedup vs baseline: 1.1380x; 1.0308x over previous
//
#include <hip/hip_runtime.h>
#include <stdint.h>

#define NN 50000   // nodes
#define NE 100000  // edges
#define DD 768     // feature dim
#define KC 1536    // concatenated K = 2*DD
#define SCAN_B 196 // ceil(NN/256)
#define BM 128
#define BN 256
#define BK 64
#define NTM 391    // ceil(NN/128)
#define NTN 3      // DD/256

typedef __attribute__((ext_vector_type(8))) __bf16 bf16x8;
typedef __attribute__((ext_vector_type(4))) float floatx4;

static __device__ __forceinline__ float bf2f(unsigned short u) {
    union { unsigned int u; float f; } c; c.u = ((unsigned int)u) << 16; return c.f;
}
static __device__ __forceinline__ unsigned short f2bf(float f) {
    union { float f; unsigned int u; } c; c.f = f;
    return (unsigned short)((c.u + 0x7FFFu + ((c.u >> 16) & 1u)) >> 16);
}

// async global->LDS, 16B per lane; LDS dst = wave-uniform base + lane*16
static __device__ __forceinline__ void gld16(const void* g, void* l) {
    __builtin_amdgcn_global_load_lds(
        (const __attribute__((address_space(1))) unsigned int*)g,
        (__attribute__((address_space(3))) unsigned int*)l, 16, 0, 0);
}

// ---------------- prep kernels ----------------

// x (f32) -> bf16 into right half of Acat1 ([n][768..1535])
__global__ __launch_bounds__(192) void k_convert_x(const float* __restrict__ x,
                                                   unsigned short* __restrict__ acat) {
    const int n = blockIdx.x;
    const int c = threadIdx.x * 4;
    const float4 v = *(const float4*)(x + (size_t)n * DD + c);
    ushort4 o;
    o.x = f2bf(v.x); o.y = f2bf(v.y); o.z = f2bf(v.z); o.w = f2bf(v.w);
    *(ushort4*)(acat + (size_t)n * KC + DD + c) = o;
}

// Bcat[layer][j][k] = k<768 ? Wl[j][k] : Wr[j][k-768]   (bf16)
__global__ __launch_bounds__(384) void k_convert_w(const float* __restrict__ W1l,
                                                   const float* __restrict__ W1r,
                                                   const float* __restrict__ W2l,
                                                   const float* __restrict__ W2r,
                                                   unsigned short* __restrict__ B1,
                                                   unsigned short* __restrict__ B2) {
    const int j = blockIdx.x;
    const int layer = blockIdx.y;
    const int k = threadIdx.x * 4;
    const float* Wl = layer ? W2l : W1l;
    const float* Wr = layer ? W2r : W1r;
    unsigned short* B = layer ? B2 : B1;
    const float4 v = (k < DD) ? *(const float4*)(Wl + (size_t)j * DD + k)
                              : *(const float4*)(Wr + (size_t)j * DD + (k - DD));
    ushort4 o; o.x = f2bf(v.x); o.y = f2bf(v.y); o.z = f2bf(v.z); o.w = f2bf(v.w);
    *(ushort4*)(B + (size_t)j * KC + k) = o;
}

// ---------------- CSR build (by dst) ----------------

__global__ __launch_bounds__(256) void k_hist(const int* __restrict__ dst,
                                              int* __restrict__ cnt) {
    int e = blockIdx.x * 256 + threadIdx.x;
    if (e < NE) atomicAdd(&cnt[dst[e]], 1);
}

// hierarchical scan, stage 1: per-block inclusive scan of 256-elem chunks
__global__ __launch_bounds__(256) void k_scan1(const int* __restrict__ cnt,
                                               int* __restrict__ rowptr,
                                               int* __restrict__ partial) {
    __shared__ int buf[256];
    const int t = threadIdx.x;
    const int i = blockIdx.x * 256 + t;
    int v = (i < NN) ? cnt[i] : 0;
    buf[t] = v;
    __syncthreads();
#pragma unroll
    for (int off = 1; off < 256; off <<= 1) {
        int u = (t >= off) ? buf[t - off] : 0;
        __syncthreads();
        buf[t] += u;
        __syncthreads();
    }
    if (i < NN) rowptr[i + 1] = buf[t];
    if (t == 255) partial[blockIdx.x] = buf[255];
}

// stage 2: single block, exclusive scan of SCAN_B partials
__global__ __launch_bounds__(256) void k_scan2(int* __restrict__ partial) {
    __shared__ int buf[256];
    const int t = threadIdx.x;
    int v = (t < SCAN_B) ? partial[t] : 0;
    buf[t] = v;
    __syncthreads();
#pragma unroll
    for (int off = 1; off < 256; off <<= 1) {
        int u = (t >= off) ? buf[t - off] : 0;
        __syncthreads();
        buf[t] += u;
        __syncthreads();
    }
    if (t < SCAN_B) partial[t] = buf[t] - v;  // exclusive
}

// stage 3: add block offsets, set rowptr[0]
__global__ __launch_bounds__(256) void k_scan3(int* __restrict__ rowptr,
                                               const int* __restrict__ partial) {
    const int i = blockIdx.x * 256 + threadIdx.x;
    if (i < NN) rowptr[i + 1] += partial[blockIdx.x];
    if (i == 0) rowptr[0] = 0;
}

__global__ __launch_bounds__(256) void k_fill(const int* __restrict__ src,
                                              const int* __restrict__ dst,
                                              const int* __restrict__ rowptr,
                                              int* __restrict__ cursor,
                                              int* __restrict__ esrc) {
    int e = blockIdx.x * 256 + threadIdx.x;
    if (e < NE) {
        const int d = dst[e];
        const int pos = atomicAdd(&cursor[d], 1);
        esrc[rowptr[d] + pos] = src[e];
    }
}

// ---------------- aggregation by gather (no atomics) ----------------
__global__ __launch_bounds__(192) void k_agg(const unsigned short* __restrict__ srcmat,
                                             const int* __restrict__ rowptr,
                                             const int* __restrict__ esrc,
                                             unsigned short* __restrict__ dstmat) {
    const int n = blockIdx.x;
    const int c = threadIdx.x * 4;
    const int beg = rowptr[n], end = rowptr[n + 1];
    float4 a = {0.f, 0.f, 0.f, 0.f};
    for (int e = beg; e < end; ++e) {
        const int s = esrc[e];
        const ushort4 v = *(const ushort4*)(srcmat + (size_t)s * KC + DD + c);
        a.x += bf2f(v.x); a.y += bf2f(v.y); a.z += bf2f(v.z); a.w += bf2f(v.w);
    }
    const float inv = (end > beg) ? 1.0f / (float)(end - beg) : 1.0f;
    ushort4 o;
    o.x = f2bf(a.x * inv); o.y = f2bf(a.y * inv);
    o.z = f2bf(a.z * inv); o.w = f2bf(a.w * inv);
    *(ushort4*)(dstmat + (size_t)n * KC + c) = o;
}

// ---------------- GEMM: C[M x 768] = A[M x 1536] * B[768 x 1536]^T + bias ----
// Round 7: barrier diet. r6 (8-wave phase-interleave) moved 236->191us,
// MfmaUtil 20.5->25.3 — first structural win, but per-phase time 2084cyc vs
// 621cyc MFMA: ~1100cyc/phase is sync machinery (4 barriers + 2 vmcnt per
// K-tile + sched_barrier fences blocking read/MFMA overlap). The 3-slot
// discipline makes ONE barrier + ONE vmcnt(6) per K-tile race-free:
//  - staging in segment t writes slot (t+2)%3 = slot of tile t-1, whose
//    reads were all lgkm-drained into MFMAs BEFORE the boundary barrier;
//    stage is issued after the barrier in program order -> no WAR race.
//  - vmcnt(6) at the boundary drains tile t's 6 loads (issued 2 segments
//    ago, ~5000cyc of cover); tile t+1's 6 loads stay in flight (T4).
// Segment body has NO internal fences: 16 ds_reads (both ksubs), 6 gld16,
// then setprio(1) 32 MFMA setprio(0). Compiler's fine-grained lgkmcnt lets
// MFMA(ksub0) overlap ksub1's read latency; waves slip within the segment.
// Carried: chunk-XOR swizzle (conflicts 0), XCD-chunked tn-fast map
// (FETCH 126MB), 128x256 tile, 8 waves (2Mx4N), wave-tile 64x64.
// MODE 0: +bias, relu, store bf16 into right half of Acat2
// MODE 1: +bias, store f32 to out
template <int MODE>
__global__ __launch_bounds__(512) void k_gemm(const unsigned short* __restrict__ A,
                                              const unsigned short* __restrict__ B,
                                              const float* __restrict__ bias,
                                              unsigned short* __restrict__ outA,
                                              float* __restrict__ outF) {
    // 3 K-tile slots: A 128x64 (16KB) + B 256x64 (32KB) each -> 144KB total
    __shared__ alignas(16) unsigned short sA[3][BM * BK];
    __shared__ alignas(16) unsigned short sB[3][BN * BK];
    const int tid = threadIdx.x;
    const int w = tid >> 6, lane = tid & 63;
    const int quad = lane >> 4, r16 = lane & 15;
    const int wr = w >> 2, wc = w & 3;      // 2M x 4N wave grid
    const int wm = wr * 64, wn = wc * 64;   // wave-tile 64x64

    // bijective XCD-aware remap (m204); tn fast (3 blocks share one A-panel)
    const int nwg = NTM * NTN;              // 1173
    const int q = nwg >> 3, r = nwg & 7;
    const int xcd = blockIdx.x & 7, slot = blockIdx.x >> 3;
    const int L = (xcd < r ? xcd * (q + 1) : r * (q + 1) + (xcd - r) * q) + slot;
    const int tn = L % NTN;
    const int tm = L / NTN;
    const int rowBase = tm * BM;

    floatx4 acc[4][4];
#pragma unroll
    for (int i = 0; i < 4; ++i)
#pragma unroll
        for (int j = 0; j < 4; ++j) acc[i][j] = (floatx4){0.f, 0.f, 0.f, 0.f};

    // staging source pointers, pre-swizzled (m173): chunk c = l*512+tid,
    // row = c>>3, physical col-chunk (c&7) receives global chunk (c&7)^(row&7)
    const unsigned short* aS[2];
    const unsigned short* bS[4];
#pragma unroll
    for (int l = 0; l < 2; ++l) {
        const int c = l * 512 + tid;
        const int row = c >> 3;
        const int jd = ((c & 7) ^ (row & 7)) * 8;
        int gr = rowBase + row; if (gr > NN - 1) gr = NN - 1;  // clamp tail tile
        aS[l] = A + (size_t)gr * KC + jd;
    }
#pragma unroll
    for (int l = 0; l < 4; ++l) {
        const int c = l * 512 + tid;
        const int row = c >> 3;
        const int jd = ((c & 7) ^ (row & 7)) * 8;
        bS[l] = B + (size_t)(tn * BN + row) * KC + jd;
    }

    // stage one full K-tile into slot d: 6 gld16 per lane, then advance K
    auto stageK = [&](int d) {
        gld16(aS[0], &sA[d][(0 * 512 + w * 64) * 8]);
        gld16(aS[1], &sA[d][(1 * 512 + w * 64) * 8]);
        gld16(bS[0], &sB[d][(0 * 512 + w * 64) * 8]);
        gld16(bS[1], &sB[d][(1 * 512 + w * 64) * 8]);
        gld16(bS[2], &sB[d][(2 * 512 + w * 64) * 8]);
        gld16(bS[3], &sB[d][(3 * 512 + w * 64) * 8]);
        aS[0] += BK; aS[1] += BK;
        bS[0] += BK; bS[1] += BK; bS[2] += BK; bS[3] += BK;
    };

    const int pc0 = ((0 * 4 + quad) ^ (r16 & 7)) * 8;  // swizzled chunk, ksub 0
    const int pc1 = ((1 * 4 + quad) ^ (r16 & 7)) * 8;  // swizzled chunk, ksub 1

    // one K-tile segment: all reads, stage (optional), 32 MFMA. No internal
    // barriers/fences — compiler schedules lgkmcnt; waves slip freely.
    auto seg = [&](int s, int d, int doStage) {
        bf16x8 a0[4], b0[4], a1[4], b1[4];
#pragma unroll
        for (int mf = 0; mf < 4; ++mf)
            a0[mf] = *(const bf16x8*)(&sA[s][(wm + mf * 16 + r16) * BK + pc0]);
#pragma unroll
        for (int nf = 0; nf < 4; ++nf)
            b0[nf] = *(const bf16x8*)(&sB[s][(wn + nf * 16 + r16) * BK + pc0]);
#pragma unroll
        for (int mf = 0; mf < 4; ++mf)
            a1[mf] = *(const bf16x8*)(&sA[s][(wm + mf * 16 + r16) * BK + pc1]);
#pragma unroll
        for (int nf = 0; nf < 4; ++nf)
            b1[nf] = *(const bf16x8*)(&sB[s][(wn + nf * 16 + r16) * BK + pc1]);
        if (doStage) stageK(d);
        __builtin_amdgcn_s_setprio(1);
#pragma unroll
        for (int mf = 0; mf < 4; ++mf)
#pragma unroll
            for (int nf = 0; nf < 4; ++nf)
                acc[mf][nf] = __builtin_amdgcn_mfma_f32_16x16x32_bf16(a0[mf], b0[nf], acc[mf][nf], 0, 0, 0);
#pragma unroll
        for (int mf = 0; mf < 4; ++mf)
#pragma unroll
            for (int nf = 0; nf < 4; ++nf)
                acc[mf][nf] = __builtin_amdgcn_mfma_f32_16x16x32_bf16(a1[mf], b1[nf], acc[mf][nf], 0, 0, 0);
        __builtin_amdgcn_s_setprio(0);
    };

    // boundary: counted drain (tile about to be read is resident; next
    // tile's 6 loads stay in flight) + single workgroup barrier.
#define BND(N)                                            \
    do {                                                  \
        __builtin_amdgcn_sched_barrier(0);                \
        asm volatile("s_waitcnt vmcnt(" #N ")" ::: "memory"); \
        __builtin_amdgcn_s_barrier();                     \
    } while (0)

    // 24 K-tiles, slot = t%3, staging targets slot (t+2)%3.
    stageK(0); stageK(1);  // tiles 0,1 (12 loads in flight)
#pragma unroll 1
    for (int g = 0; g < 7; ++g) {       // t = 0..20
        BND(6); seg(0, 2, 1);
        BND(6); seg(1, 0, 1);
        BND(6); seg(2, 1, 1);
    }
    BND(6); seg(0, 2, 1);   // t=21: stages tile 23 -> slot 2
    BND(6); seg(1, 0, 0);   // t=22
    BND(0); seg(2, 0, 0);   // t=23: final tile (drain all)
#undef BND

    // epilogue: C/D layout col=lane&15, row=quad*4+reg
#pragma unroll
    for (int mf = 0; mf < 4; ++mf)
#pragma unroll
        for (int nf = 0; nf < 4; ++nf) {
            const int gcol = tn * BN + wn + nf * 16 + r16;
            const float bv = bias[gcol];
#pragma unroll
            for (int rr = 0; rr < 4; ++rr) {
                const int grow = rowBase + wm + mf * 16 + quad * 4 + rr;
                if (grow < NN) {
                    float v = acc[mf][nf][rr] + bv;
                    if (MODE == 0) {
                        v = fmaxf(v, 0.0f);
                        outA[(size_t)grow * KC + DD + gcol] = f2bf(v);
                    } else {
                        outF[(size_t)grow * DD + gcol] = v;
                    }
                }
            }
        }
}

extern "C" void kernel_launch(void* const* d_in, const int* in_sizes, int n_in,
                              void* d_out, int out_size, void* d_ws, size_t ws_size,
                              hipStream_t stream) {
    const float* x   = (const float*)d_in[0];
    const int*   ei  = (const int*)d_in[1];
    const float* W1l = (const float*)d_in[2];
    const float* b1l = (const float*)d_in[3];
    const float* W1r = (const float*)d_in[4];
    const float* W2l = (const float*)d_in[5];
    const float* b2l = (const float*)d_in[6];
    const float* W2r = (const float*)d_in[7];
    const int* src = ei;
    const int* dst = ei + NE;
    float* out = (float*)d_out;

    // ws layout (~310 MB):
    //   Acat1: [N x 1536] bf16  (left=agg1, right=bf16(x))
    //   Acat2: [N x 1536] bf16  (left=agg2, right=h)
    //   B1,B2: [768 x 1536] bf16 each
    //   CSR:   cnt[N] (reused as cursor), rowptr[N+1], esrc[E], partial[SCAN_B]
    char* ws = (char*)d_ws;
    unsigned short* Acat1 = (unsigned short*)ws;
    unsigned short* Acat2 = (unsigned short*)(ws + (size_t)NN * KC * 2);
    unsigned short* B1    = (unsigned short*)(ws + (size_t)NN * KC * 4);
    unsigned short* B2    = B1 + (size_t)DD * KC;
    int* cnt    = (int*)(ws + (size_t)NN * KC * 4 + (size_t)DD * KC * 4);
    int* rowptr = cnt + NN;
    int* esrc   = rowptr + NN + 1;
    int* partial = esrc + NE;

    // CSR build (hierarchical scan; no single-block serialization)
    hipMemsetAsync(cnt, 0, NN * sizeof(int), stream);
    k_hist<<<(NE + 255) / 256, 256, 0, stream>>>(dst, cnt);
    k_scan1<<<SCAN_B, 256, 0, stream>>>(cnt, rowptr, partial);
    k_scan2<<<1, 256, 0, stream>>>(partial);
    k_scan3<<<SCAN_B, 256, 0, stream>>>(rowptr, partial);
    hipMemsetAsync(cnt, 0, NN * sizeof(int), stream);  // reuse as cursor
    k_fill<<<(NE + 255) / 256, 256, 0, stream>>>(src, dst, rowptr, cnt, esrc);

    // converts
    k_convert_x<<<NN, 192, 0, stream>>>(x, Acat1);
    dim3 wgrid(DD, 2);
    k_convert_w<<<wgrid, 384, 0, stream>>>(W1l, W1r, W2l, W2r, B1, B2);

    const int ggrid = NTM * NTN;  // 1173 blocks, XCD-chunked tn-fast mapping inside

    // layer 1 (aggregate bf16(x) from right half of Acat1)
    k_agg<<<NN, 192, 0, stream>>>(Acat1, rowptr, esrc, Acat1);
    k_gemm<0><<<ggrid, 512, 0, stream>>>(Acat1, B1, b1l, Acat2, nullptr);

    // layer 2
    k_agg<<<NN, 192, 0, stream>>>(Acat2, rowptr, esrc, Acat2);
    k_gemm<1><<<ggrid, 512, 0, stream>>>(Acat2, B2, b2l, nullptr, out);
}